// Round 7
// baseline (164.038 us; speedup 1.0000x reference)
//
#include <hip/hip_runtime.h>
#include <stdint.h>

// ---------------------------------------------------------------------------
// MoEBiEncoder: top-1 MoE (C=16 experts), per-row 768 -> relu(384) -> 768,
// gate-scale, l2norm, +residual, l2norm.  B=16384, D=768, H=384.
//
// v7: phase-chain elimination. moe_main split into two barrier-free
//     streaming kernels (S1: emb->h, S2: h->out) with h in workspace (bf16).
//     A-fragments are loaded DIRECTLY into registers (no LDS staging, no
//     stage barriers): S1 from gathered emb rows (per-lane row pointers),
//     S2 from the L1-resident 24 KB h tile. All prior rounds (81-92us,
//     all pipes <20%) shared the serial 6-phase barrier chain - removed.
// ---------------------------------------------------------------------------

#define B_ROWS 16384
#define C_EXP  16
#define D_DIM  768
#define H_DIM  384

typedef __bf16 bf16_t;
typedef __bf16 bf16x8 __attribute__((ext_vector_type(8)));
typedef float  f32x4  __attribute__((ext_vector_type(4)));

// ---- workspace layout (bytes) ----
static constexpr size_t WS_CNT  = 0;                       // 16 int
static constexpr size_t WS_CUR  = 64;                      // 16 int
static constexpr size_t WS_OFF  = 128;                     // 17 int
static constexpr size_t WS_TOFF = 256;                     // 17 int
static constexpr size_t WS_EXP  = 512;                     // B int
static constexpr size_t WS_GATE = WS_EXP  + (size_t)B_ROWS * 4;
static constexpr size_t WS_ROW  = WS_GATE + (size_t)B_ROWS * 4;
static constexpr size_t WS_W1   = WS_ROW  + (size_t)B_ROWS * 4;
static constexpr size_t W_BYTES = (size_t)C_EXP * D_DIM * H_DIM * 2;  // 9437184
static constexpr size_t WS_W4   = WS_W1 + W_BYTES;
static constexpr size_t WS_H    = WS_W4 + W_BYTES;
static constexpr size_t H_TILE  = 32 * H_DIM * 2;          // 24576 B per tile
static constexpr size_t WS_END  = WS_H + 527 * H_TILE;     // ~30.7 MB

// Fragment-major weight layout (per expert, KF = K/32, NF = N/16):
//   frag(kf,nf) = 1024 contiguous bytes; lane l's 16B at l*16 hold
//   w[k0 + (l>>4)*8 + j][n0 + (l&15)], j=0..7.
// w1: KF=24, NF=24.  w4: KF=12, NF=48.
// MFMA A-operand (verified by R1-R6 passing): lane l's bf16x8 holds
//   A[r0 + (l&15)][k0 + (l>>4)*8 + j], j=0..7.

__device__ __forceinline__ f32x4 mfma16(bf16x8 a, bf16x8 b, f32x4 c) {
    return __builtin_amdgcn_mfma_f32_16x16x32_bf16(a, b, c, 0, 0, 0);
}

// ---------------------------------------------------------------------------
// Kernel 1 "prep": blocks 0..2303 convert weights; blocks 2304..2335 do the
// gate (softmax/argmax) + per-expert counts via LDS histogram.
// ---------------------------------------------------------------------------
__global__ __launch_bounds__(512) void prep(const float* __restrict__ w1,
                                            const float* __restrict__ w4,
                                            const float* __restrict__ logits,
                                            char* __restrict__ w1s,
                                            char* __restrict__ w4s,
                                            int* __restrict__ expert,
                                            float* __restrict__ gatev,
                                            int* __restrict__ cnt) {
    __shared__ float tile[64 * 65];
    __shared__ int   hist[16];
    int bid = blockIdx.x;

    if (bid >= 2304) {
        // ---------------- gate part: 32 blocks x 512 threads --------------
        if (threadIdx.x < 16) hist[threadIdx.x] = 0;
        __syncthreads();
        int b = (bid - 2304) * 512 + threadIdx.x;   // 0..16383
        const f32x4* lp = (const f32x4*)(logits + (size_t)b * C_EXP);
        float l[16];
#pragma unroll
        for (int i = 0; i < 4; ++i) {
            f32x4 v = lp[i];
            l[i*4+0] = v[0]; l[i*4+1] = v[1]; l[i*4+2] = v[2]; l[i*4+3] = v[3];
        }
        float m = l[0]; int idx = 0;
#pragma unroll
        for (int j = 1; j < 16; ++j)
            if (l[j] > m) { m = l[j]; idx = j; }   // first-max == np.argmax
        float s = 0.f;
#pragma unroll
        for (int j = 0; j < 16; ++j) s += __expf((l[j] - m) * 0.1f);
        expert[b] = idx;
        gatev[b]  = 1.0f / s;          // softmax value at the argmax
        atomicAdd(&hist[idx], 1);      // LDS atomic (fast)
        __syncthreads();
        if (threadIdx.x < 16) {
            int c = hist[threadIdx.x];
            if (c) atomicAdd(&cnt[threadIdx.x], c);   // <=16 global atomics/blk
        }
        return;
    }

    // ---------------- weight convert: fp32 [K][N] -> bf16 fragment-major --
    bool is1 = bid < 1152;
    int lb = is1 ? bid : bid - 1152;
    int c = lb / 72, rem = lb % 72;
    int kc, nb, Nfull, KF, NF;
    const float* src;
    char* dstbase;
    if (is1) {
        kc = rem / 6;  nb = rem % 6;  Nfull = H_DIM; KF = 24; NF = 24;
        src     = w1 + (size_t)c * D_DIM * H_DIM;
        dstbase = w1s;
    } else {
        kc = rem / 12; nb = rem % 12; Nfull = D_DIM; KF = 12; NF = 48;
        src     = w4 + (size_t)c * H_DIM * D_DIM;
        dstbase = w4s;
    }
    // read 64(k) x 64(n) fp32 tile, coalesced along n
#pragma unroll
    for (int it = 0; it < 2; ++it) {
        int f  = threadIdx.x + it * 512;   // float4 id 0..1023
        int kr = f >> 4, nq = f & 15;
        f32x4 v = *(const f32x4*)(src + (size_t)(kc * 64 + kr) * Nfull + nb * 64 + nq * 4);
        tile[kr * 65 + nq * 4 + 0] = v[0];
        tile[kr * 65 + nq * 4 + 1] = v[1];
        tile[kr * 65 + nq * 4 + 2] = v[2];
        tile[kr * 65 + nq * 4 + 3] = v[3];
    }
    __syncthreads();
    // write 8 fragments (one per 64-thread group), 16B/lane coalesced
    {
        int frag = threadIdx.x >> 6, lane = threadIdx.x & 63;
        int kfl  = frag >> 2, nfl = frag & 3;
        int col  = lane & 15, kq = lane >> 4;
        bf16x8 p;
#pragma unroll
        for (int j = 0; j < 8; ++j)
            p[j] = (bf16_t)tile[(kfl * 32 + kq * 8 + j) * 65 + nfl * 16 + col];
        int kf = kc * 2 + kfl, nf = nb * 4 + nfl;
        size_t off = (((size_t)c * KF + kf) * NF + nf) * 1024 + lane * 16;
        *(bf16x8*)(dstbase + off) = p;
    }
}

// ---------------------------------------------------------------------------
// Kernel 2: tiny serial scan (16 experts), 32-row tiles.
// ---------------------------------------------------------------------------
__global__ void scank(const int* __restrict__ cnt, int* __restrict__ offs,
                      int* __restrict__ toff) {
    if (threadIdx.x == 0 && blockIdx.x == 0) {
        int o = 0, to = 0;
        for (int e = 0; e < C_EXP; ++e) {
            offs[e] = o; toff[e] = to;
            o  += cnt[e];
            to += (cnt[e] + 31) >> 5;
        }
        offs[C_EXP] = o; toff[C_EXP] = to;
    }
}

// ---------------------------------------------------------------------------
// Kernel 3: bucket rows by expert (hierarchical: LDS rank + 16 atomics/blk).
// ---------------------------------------------------------------------------
__global__ __launch_bounds__(512) void scatk(const int* __restrict__ expert,
                                             const int* __restrict__ offs,
                                             int* __restrict__ cursor,
                                             int* __restrict__ rowlist) {
    __shared__ int lcur[16], lbase[16];
    int b = blockIdx.x * 512 + threadIdx.x;   // grid 32 -> 0..16383
    if (threadIdx.x < 16) lcur[threadIdx.x] = 0;
    __syncthreads();
    int e = expert[b];
    int p = atomicAdd(&lcur[e], 1);           // LDS atomic
    __syncthreads();
    if (threadIdx.x < 16) {
        int c = lcur[threadIdx.x];
        lbase[threadIdx.x] = c ? atomicAdd(&cursor[threadIdx.x], c) : 0;
    }
    __syncthreads();
    rowlist[offs[e] + lbase[e] + p] = b;
}

// ---------------------------------------------------------------------------
// Kernel S1: h = relu(emb @ w1 + b1) for one 32-row tile -> hws (bf16).
// 512 threads = 8 waves; wave w owns h cols [w*48, w*48+48) (3 frags), 2 rgs.
// NO LDS staging: A-fragments loaded per-lane directly from gathered emb
// rows (fp32 -> bf16 cvt in regs). One barrier total (ridx table).
// ---------------------------------------------------------------------------
__global__ __launch_bounds__(512) void moe_s1(
    const float* __restrict__ emb, const int* __restrict__ rowlist,
    const int* __restrict__ cnt, const int* __restrict__ offs,
    const int* __restrict__ toff, const char* __restrict__ w1s,
    const float* __restrict__ b1, char* __restrict__ hws) {
    __shared__ int ridxL[32];

    int bid = blockIdx.x;                    // grid 528 = 8*66
    int t   = (bid & 7) * 66 + (bid >> 3);   // XCD-contiguous tiles
    if (t >= toff[C_EXP]) return;
    int e = 0;
#pragma unroll
    for (int i = 1; i < C_EXP; ++i) e = (t >= toff[i]) ? i : e;
    int tin  = t - toff[e];
    int Meff = cnt[e] - tin * 32; if (Meff > 32) Meff = 32;
    int base = offs[e] + tin * 32;

    if (threadIdx.x < 32) {
        int rr = threadIdx.x;
        ridxL[rr] = rowlist[base + (rr < Meff ? rr : 0)];
    }
    __syncthreads();   // the only block-wide barrier

    const int wid = threadIdx.x >> 6;
    const int lane = threadIdx.x & 63;
    const int l15 = lane & 15, l4 = lane >> 4;

    // per-lane row pointers for the two 16-row groups (hoisted)
    const float* rp0 = emb + (size_t)ridxL[l15] * D_DIM + l4 * 8;
    const float* rp1 = emb + (size_t)ridxL[16 + l15] * D_DIM + l4 * 8;
    const char*  w1e = w1s + (size_t)e * 589824;

    f32x4 acc[2][3];
#pragma unroll
    for (int rg = 0; rg < 2; ++rg)
#pragma unroll
        for (int j = 0; j < 3; ++j) acc[rg][j] = f32x4{0.f, 0.f, 0.f, 0.f};

#pragma unroll
    for (int kf = 0; kf < 24; ++kf) {
        // A-fragments straight from global (gathered rows), cvt to bf16
        f32x4 a00 = *(const f32x4*)(rp0 + kf * 32);
        f32x4 a01 = *(const f32x4*)(rp0 + kf * 32 + 4);
        f32x4 a10 = *(const f32x4*)(rp1 + kf * 32);
        f32x4 a11 = *(const f32x4*)(rp1 + kf * 32 + 4);
        bf16x8 A0, A1;
#pragma unroll
        for (int j = 0; j < 4; ++j) {
            A0[j] = (bf16_t)a00[j]; A0[4 + j] = (bf16_t)a01[j];
            A1[j] = (bf16_t)a10[j]; A1[4 + j] = (bf16_t)a11[j];
        }
        bf16x8 b0 = *(const bf16x8*)(w1e + (size_t)(kf * 24 + wid * 3 + 0) * 1024 + lane * 16);
        bf16x8 b1f = *(const bf16x8*)(w1e + (size_t)(kf * 24 + wid * 3 + 1) * 1024 + lane * 16);
        bf16x8 b2f = *(const bf16x8*)(w1e + (size_t)(kf * 24 + wid * 3 + 2) * 1024 + lane * 16);
        acc[0][0] = mfma16(A0, b0,  acc[0][0]);
        acc[1][0] = mfma16(A1, b0,  acc[1][0]);
        acc[0][1] = mfma16(A0, b1f, acc[0][1]);
        acc[1][1] = mfma16(A1, b1f, acc[1][1]);
        acc[0][2] = mfma16(A0, b2f, acc[0][2]);
        acc[1][2] = mfma16(A1, b2f, acc[1][2]);
    }

    // h = relu(acc + b1) -> hws tile [32][384] bf16 (row stride 768 B)
    char* ht = hws + (size_t)t * H_TILE;
#pragma unroll
    for (int jn = 0; jn < 3; ++jn) {
        int col = wid * 48 + jn * 16 + l15;
        float bb = b1[e * H_DIM + col];
#pragma unroll
        for (int rg = 0; rg < 2; ++rg)
#pragma unroll
            for (int v = 0; v < 4; ++v) {
                int row = rg * 16 + l4 * 4 + v;
                float hv = fmaxf(acc[rg][jn][v] + bb, 0.f);
                *(bf16_t*)(ht + row * 768 + col * 2) = (bf16_t)hv;
            }
    }
}

// ---------------------------------------------------------------------------
// Kernel S2: out = l2norm(l2norm(gate*(h @ w4 + b4)) + emb) for one tile.
// 512 threads = 8 waves; wave w owns out cols [w*96, w*96+96) (6 frags).
// A-fragments loaded per-lane directly from the 24 KB h tile (L1-resident
// after the first wave touches it). Barriers only for the two reductions.
// ---------------------------------------------------------------------------
__global__ __launch_bounds__(512) void moe_s2(
    const float* __restrict__ emb, const float* __restrict__ gatev,
    const int* __restrict__ rowlist, const int* __restrict__ cnt,
    const int* __restrict__ offs, const int* __restrict__ toff,
    const char* __restrict__ w4s, const float* __restrict__ b4,
    const char* __restrict__ hws, float* __restrict__ out) {
    __shared__ float ssb1[32 * 8], ssb2[32 * 8];
    __shared__ int   ridxL[32];
    __shared__ float gateL[32];

    int bid = blockIdx.x;
    int t   = (bid & 7) * 66 + (bid >> 3);
    if (t >= toff[C_EXP]) return;
    int e = 0;
#pragma unroll
    for (int i = 1; i < C_EXP; ++i) e = (t >= toff[i]) ? i : e;
    int tin  = t - toff[e];
    int Meff = cnt[e] - tin * 32; if (Meff > 32) Meff = 32;
    int base = offs[e] + tin * 32;

    if (threadIdx.x < 32) {
        int rr = threadIdx.x;
        int ri = rowlist[base + (rr < Meff ? rr : 0)];
        ridxL[rr] = ri;
        gateL[rr] = gatev[ri];
    }
    __syncthreads();

    const int wid = threadIdx.x >> 6;
    const int lane = threadIdx.x & 63;
    const int l15 = lane & 15, l4 = lane >> 4;

    const char* ht  = hws + (size_t)t * H_TILE;
    const char* hp0 = ht + l15 * 768 + l4 * 16;          // rg0 row, k-slice
    const char* hp1 = ht + (16 + l15) * 768 + l4 * 16;   // rg1
    const char* w4e = w4s + (size_t)e * 589824;

    f32x4 acc[2][6];
#pragma unroll
    for (int rg = 0; rg < 2; ++rg)
#pragma unroll
        for (int j = 0; j < 6; ++j) acc[rg][j] = f32x4{0.f, 0.f, 0.f, 0.f};

#pragma unroll
    for (int kf = 0; kf < 12; ++kf) {
        bf16x8 A0 = *(const bf16x8*)(hp0 + kf * 64);
        bf16x8 A1 = *(const bf16x8*)(hp1 + kf * 64);
#pragma unroll
        for (int jn = 0; jn < 6; ++jn) {
            bf16x8 b = *(const bf16x8*)(w4e + (size_t)(kf * 48 + wid * 6 + jn) * 1024 + lane * 16);
            acc[0][jn] = mfma16(A0, b, acc[0][jn]);
            acc[1][jn] = mfma16(A1, b, acc[1][jn]);
        }
    }

    // ---------------- epilogue: gate, l2norm, +emb, l2norm, scatter -------
    const int colb = wid * 96;
    float part[2][4];
#pragma unroll
    for (int rg = 0; rg < 2; ++rg)
#pragma unroll
        for (int v = 0; v < 4; ++v) part[rg][v] = 0.f;

#pragma unroll
    for (int jn = 0; jn < 6; ++jn) {
        float bb = b4[e * D_DIM + colb + jn * 16 + l15];
#pragma unroll
        for (int rg = 0; rg < 2; ++rg)
#pragma unroll
            for (int v = 0; v < 4; ++v) {
                float cv = (acc[rg][jn][v] + bb) * gateL[rg * 16 + l4 * 4 + v];
                acc[rg][jn][v] = cv;
                part[rg][v] += cv * cv;
            }
    }
#pragma unroll
    for (int o = 1; o < 16; o <<= 1)
#pragma unroll
        for (int rg = 0; rg < 2; ++rg)
#pragma unroll
            for (int v = 0; v < 4; ++v) part[rg][v] += __shfl_xor(part[rg][v], o, 64);
    if (l15 == 0)
#pragma unroll
        for (int rg = 0; rg < 2; ++rg)
#pragma unroll
            for (int v = 0; v < 4; ++v) ssb1[(rg * 16 + l4 * 4 + v) * 8 + wid] = part[rg][v];
    __syncthreads();

    int   rofs[2][4];
    float inv1[2][4];
#pragma unroll
    for (int rg = 0; rg < 2; ++rg)
#pragma unroll
        for (int v = 0; v < 4; ++v) {
            int row = rg * 16 + l4 * 4 + v;
            rofs[rg][v] = ridxL[row] * D_DIM;
            float s = 0.f;
#pragma unroll
            for (int w = 0; w < 8; ++w) s += ssb1[row * 8 + w];
            inv1[rg][v] = 1.0f / fmaxf(sqrtf(s), 1e-6f);
        }

    float part2[2][4];
#pragma unroll
    for (int rg = 0; rg < 2; ++rg)
#pragma unroll
        for (int v = 0; v < 4; ++v) part2[rg][v] = 0.f;

#pragma unroll
    for (int jn = 0; jn < 6; ++jn) {
        int col = colb + jn * 16 + l15;
#pragma unroll
        for (int rg = 0; rg < 2; ++rg)
#pragma unroll
            for (int v = 0; v < 4; ++v) {
                float em = emb[rofs[rg][v] + col];
                float o2 = acc[rg][jn][v] * inv1[rg][v] + em;
                acc[rg][jn][v] = o2;
                part2[rg][v] += o2 * o2;
            }
    }
#pragma unroll
    for (int o = 1; o < 16; o <<= 1)
#pragma unroll
        for (int rg = 0; rg < 2; ++rg)
#pragma unroll
            for (int v = 0; v < 4; ++v) part2[rg][v] += __shfl_xor(part2[rg][v], o, 64);
    if (l15 == 0)
#pragma unroll
        for (int rg = 0; rg < 2; ++rg)
#pragma unroll
            for (int v = 0; v < 4; ++v) ssb2[(rg * 16 + l4 * 4 + v) * 8 + wid] = part2[rg][v];
    __syncthreads();

#pragma unroll
    for (int rg = 0; rg < 2; ++rg)
#pragma unroll
        for (int v = 0; v < 4; ++v) {
            int row = rg * 16 + l4 * 4 + v;
            float s = 0.f;
#pragma unroll
            for (int w = 0; w < 8; ++w) s += ssb2[row * 8 + w];
            float inv2 = 1.0f / fmaxf(sqrtf(s), 1e-12f);
            if (row < Meff) {
#pragma unroll
                for (int jn = 0; jn < 6; ++jn)
                    out[rofs[rg][v] + colb + jn * 16 + l15] = acc[rg][jn][v] * inv2;
            }
        }
}

// ---------------------------------------------------------------------------
extern "C" void kernel_launch(void* const* d_in, const int* in_sizes, int n_in,
                              void* d_out, int out_size, void* d_ws, size_t ws_size,
                              hipStream_t stream) {
    const float* emb    = (const float*)d_in[0];
    const float* logits = (const float*)d_in[1];
    const float* w1     = (const float*)d_in[2];
    const float* b1     = (const float*)d_in[3];
    const float* w4     = (const float*)d_in[4];
    const float* b4     = (const float*)d_in[5];
    float* out = (float*)d_out;
    char*  ws  = (char*)d_ws;
    if (ws_size < WS_END) return;  // workspace too small -> fail loudly

    int*   cnt     = (int*)(ws + WS_CNT);
    int*   cur     = (int*)(ws + WS_CUR);
    int*   offs    = (int*)(ws + WS_OFF);
    int*   toff    = (int*)(ws + WS_TOFF);
    int*   expert  = (int*)(ws + WS_EXP);
    float* gatev   = (float*)(ws + WS_GATE);
    int*   rowlist = (int*)(ws + WS_ROW);
    char*  w1s     = ws + WS_W1;
    char*  w4s     = ws + WS_W4;
    char*  hws     = ws + WS_H;

    hipMemsetAsync(ws, 0, 512, stream);
    // weights convert (2304 blocks) + gate (32 blocks) in one dispatch
    prep<<<dim3(2336), dim3(512), 0, stream>>>(w1, w4, logits, w1s, w4s,
                                               expert, gatev, cnt);
    scank<<<dim3(1), dim3(64), 0, stream>>>(cnt, offs, toff);
    scatk<<<dim3(32), dim3(512), 0, stream>>>(expert, offs, cur, rowlist);

    // max tiles = sum_e ceil(cnt_e/32) <= 527; grid 528 = 8*66 (XCD swizzle)
    moe_s1<<<dim3(528), dim3(512), 0, stream>>>(
        emb, rowlist, cnt, offs, toff, w1s, b1, hws);
    moe_s2<<<dim3(528), dim3(512), 0, stream>>>(
        emb, gatev, rowlist, cnt, offs, toff, w4s, b4, hws, out);
}

// Round 8
// 145.792 us; speedup vs baseline: 1.1251x; 1.1251x over previous
//
#include <hip/hip_runtime.h>
#include <stdint.h>

// ---------------------------------------------------------------------------
// MoEBiEncoder: top-1 MoE (C=16 experts), per-row 768 -> relu(384) -> 768,
// gate-scale, l2norm, +residual, l2norm.  B=16384, D=768, H=384.
//
// v8: R5 structure (32-row tiles, A in LDS, B streamed from L2) +
//     (a) non-temporal emb/out traffic so streaming data stops evicting
//         expert weights from the per-XCD L2 (latency theory: weight loads
//         were falling to L3/HBM at ~900cy), and
//     (b) distance-4/3 B-fragment register rotation (full unroll, constant
//         indices) -> compiler emits counted vmcnt(9)/vmcnt(12), never 0.
// ---------------------------------------------------------------------------

#define B_ROWS 16384
#define C_EXP  16
#define D_DIM  768
#define H_DIM  384

typedef __bf16 bf16_t;
typedef __bf16 bf16x8 __attribute__((ext_vector_type(8)));
typedef float  f32x4  __attribute__((ext_vector_type(4)));

// ---- workspace layout (bytes) ----
static constexpr size_t WS_CNT  = 0;                       // 16 int
static constexpr size_t WS_CUR  = 64;                      // 16 int
static constexpr size_t WS_OFF  = 128;                     // 17 int
static constexpr size_t WS_TOFF = 256;                     // 17 int
static constexpr size_t WS_EXP  = 512;                     // B int
static constexpr size_t WS_GATE = WS_EXP  + (size_t)B_ROWS * 4;
static constexpr size_t WS_ROW  = WS_GATE + (size_t)B_ROWS * 4;
static constexpr size_t WS_W1   = WS_ROW  + (size_t)B_ROWS * 4;
static constexpr size_t W_BYTES = (size_t)C_EXP * D_DIM * H_DIM * 2;  // 9437184
static constexpr size_t WS_W4   = WS_W1 + W_BYTES;
static constexpr size_t WS_END  = WS_W4 + W_BYTES;         // ~18.2 MB

// Fragment-major weight layout (per expert, KF = K/32, NF = N/16):
//   frag(kf,nf) = 1024 contiguous bytes; lane l's 16B at l*16 hold
//   w[k0 + (l>>4)*8 + j][n0 + (l&15)], j=0..7.
// w1: KF=24, NF=24.  w4: KF=12, NF=48.

__device__ __forceinline__ f32x4 mfma16(bf16x8 a, bf16x8 b, f32x4 c) {
    return __builtin_amdgcn_mfma_f32_16x16x32_bf16(a, b, c, 0, 0, 0);
}

// ---------------------------------------------------------------------------
// Kernel 1 "prep": blocks 0..2303 convert weights; blocks 2304..2335 do the
// gate (softmax/argmax) + per-expert counts via LDS histogram.
// ---------------------------------------------------------------------------
__global__ __launch_bounds__(512) void prep(const float* __restrict__ w1,
                                            const float* __restrict__ w4,
                                            const float* __restrict__ logits,
                                            char* __restrict__ w1s,
                                            char* __restrict__ w4s,
                                            int* __restrict__ expert,
                                            float* __restrict__ gatev,
                                            int* __restrict__ cnt) {
    __shared__ float tile[64 * 65];
    __shared__ int   hist[16];
    int bid = blockIdx.x;

    if (bid >= 2304) {
        // ---------------- gate part: 32 blocks x 512 threads --------------
        if (threadIdx.x < 16) hist[threadIdx.x] = 0;
        __syncthreads();
        int b = (bid - 2304) * 512 + threadIdx.x;   // 0..16383
        const f32x4* lp = (const f32x4*)(logits + (size_t)b * C_EXP);
        float l[16];
#pragma unroll
        for (int i = 0; i < 4; ++i) {
            f32x4 v = lp[i];
            l[i*4+0] = v[0]; l[i*4+1] = v[1]; l[i*4+2] = v[2]; l[i*4+3] = v[3];
        }
        float m = l[0]; int idx = 0;
#pragma unroll
        for (int j = 1; j < 16; ++j)
            if (l[j] > m) { m = l[j]; idx = j; }   // first-max == np.argmax
        float s = 0.f;
#pragma unroll
        for (int j = 0; j < 16; ++j) s += __expf((l[j] - m) * 0.1f);
        expert[b] = idx;
        gatev[b]  = 1.0f / s;          // softmax value at the argmax
        atomicAdd(&hist[idx], 1);      // LDS atomic (fast)
        __syncthreads();
        if (threadIdx.x < 16) {
            int c = hist[threadIdx.x];
            if (c) atomicAdd(&cnt[threadIdx.x], c);   // <=16 global atomics/blk
        }
        return;
    }

    // ---------------- weight convert: fp32 [K][N] -> bf16 fragment-major --
    bool is1 = bid < 1152;
    int lb = is1 ? bid : bid - 1152;
    int c = lb / 72, rem = lb % 72;
    int kc, nb, Nfull, KF, NF;
    const float* src;
    char* dstbase;
    if (is1) {
        kc = rem / 6;  nb = rem % 6;  Nfull = H_DIM; KF = 24; NF = 24;
        src     = w1 + (size_t)c * D_DIM * H_DIM;
        dstbase = w1s;
    } else {
        kc = rem / 12; nb = rem % 12; Nfull = D_DIM; KF = 12; NF = 48;
        src     = w4 + (size_t)c * H_DIM * D_DIM;
        dstbase = w4s;
    }
    // read 64(k) x 64(n) fp32 tile, coalesced along n
#pragma unroll
    for (int it = 0; it < 2; ++it) {
        int f  = threadIdx.x + it * 512;   // float4 id 0..1023
        int kr = f >> 4, nq = f & 15;
        f32x4 v = *(const f32x4*)(src + (size_t)(kc * 64 + kr) * Nfull + nb * 64 + nq * 4);
        tile[kr * 65 + nq * 4 + 0] = v[0];
        tile[kr * 65 + nq * 4 + 1] = v[1];
        tile[kr * 65 + nq * 4 + 2] = v[2];
        tile[kr * 65 + nq * 4 + 3] = v[3];
    }
    __syncthreads();
    // write 8 fragments (one per 64-thread group), 16B/lane coalesced
    {
        int frag = threadIdx.x >> 6, lane = threadIdx.x & 63;
        int kfl  = frag >> 2, nfl = frag & 3;
        int col  = lane & 15, kq = lane >> 4;
        bf16x8 p;
#pragma unroll
        for (int j = 0; j < 8; ++j)
            p[j] = (bf16_t)tile[(kfl * 32 + kq * 8 + j) * 65 + nfl * 16 + col];
        int kf = kc * 2 + kfl, nf = nb * 4 + nfl;
        size_t off = (((size_t)c * KF + kf) * NF + nf) * 1024 + lane * 16;
        *(bf16x8*)(dstbase + off) = p;
    }
}

// ---------------------------------------------------------------------------
// Kernel 2: tiny serial scan (16 experts), 32-row tiles.
// ---------------------------------------------------------------------------
__global__ void scank(const int* __restrict__ cnt, int* __restrict__ offs,
                      int* __restrict__ toff) {
    if (threadIdx.x == 0 && blockIdx.x == 0) {
        int o = 0, to = 0;
        for (int e = 0; e < C_EXP; ++e) {
            offs[e] = o; toff[e] = to;
            o  += cnt[e];
            to += (cnt[e] + 31) >> 5;
        }
        offs[C_EXP] = o; toff[C_EXP] = to;
    }
}

// ---------------------------------------------------------------------------
// Kernel 3: bucket rows by expert (hierarchical: LDS rank + 16 atomics/blk).
// ---------------------------------------------------------------------------
__global__ __launch_bounds__(512) void scatk(const int* __restrict__ expert,
                                             const int* __restrict__ offs,
                                             int* __restrict__ cursor,
                                             int* __restrict__ rowlist) {
    __shared__ int lcur[16], lbase[16];
    int b = blockIdx.x * 512 + threadIdx.x;   // grid 32 -> 0..16383
    if (threadIdx.x < 16) lcur[threadIdx.x] = 0;
    __syncthreads();
    int e = expert[b];
    int p = atomicAdd(&lcur[e], 1);           // LDS atomic
    __syncthreads();
    if (threadIdx.x < 16) {
        int c = lcur[threadIdx.x];
        lbase[threadIdx.x] = c ? atomicAdd(&cursor[threadIdx.x], c) : 0;
    }
    __syncthreads();
    rowlist[offs[e] + lbase[e] + p] = b;
}

// ---------------------------------------------------------------------------
// Kernel 4: grouped GEMM + fused epilogue.
// One block = 32 rows of one expert, 512 threads = 8 waves (N-split).
// LDS (51456 B):
//   [0, 49152)  embA [32][768] bf16 swz (stage 1)
//   [0, 24576)  h    [32][384] bf16 swz (stage 2; aliases dead embA)
//   ssb1 @49152 (1 KB); ssb2 @50176 (1 KB); ridx @51200; gate @51328.
// K-loops: distance-4 (stage1) / distance-3 (stage2) B register rotation,
// fully unrolled (constant indices) -> counted vmcnt, never drained to 0.
// emb reads and out writes are non-temporal (no inter-block reuse) so the
// streams don't evict expert weights from the per-XCD L2.
// ---------------------------------------------------------------------------
#define SMEM_BYTES 51456

__global__ __launch_bounds__(512, 4) void moe_main(
    const float* __restrict__ emb, const float* __restrict__ gatev,
    const int* __restrict__ rowlist, const int* __restrict__ cnt,
    const int* __restrict__ offs, const int* __restrict__ toff,
    const char* __restrict__ w1s, const char* __restrict__ w4s,
    const float* __restrict__ b1, const float* __restrict__ b4,
    float* __restrict__ out) {
    extern __shared__ char smem[];

    // XCD-aware bijective swizzle: grid 528 = 8 * 66
    int bid = blockIdx.x;
    int t   = (bid & 7) * 66 + (bid >> 3);

    int total = toff[C_EXP];
    if (t >= total) return;
    int e = 0;
#pragma unroll
    for (int i = 1; i < C_EXP; ++i) e = (t >= toff[i]) ? i : e;
    int tin  = t - toff[e];
    int Meff = cnt[e] - tin * 32; if (Meff > 32) Meff = 32;
    int base = offs[e] + tin * 32;

    float* ssb1  = (float*)(smem + 49152);   // [32][8]
    float* ssb2  = (float*)(smem + 50176);   // [32][8]
    int*   ridxL = (int*)(smem + 51200);
    float* gateL = (float*)(smem + 51328);
    if (threadIdx.x < 32) {
        int rr = threadIdx.x;
        int p  = base + (rr < Meff ? rr : 0);   // clamp pad rows
        int ri = rowlist[p];
        ridxL[rr] = ri;
        gateL[rr] = gatev[ri];
    }
    __syncthreads();   // (1) ridxL visible

    const int wid  = threadIdx.x >> 6;
    const int lane = threadIdx.x & 63;
    const int l15  = lane & 15, l4 = lane >> 4;

    const char* w1e = w1s + (size_t)e * 589824;
    const char* w4e = w4s + (size_t)e * 589824;

    auto ldB1 = [&](int kf, int jn) {
        return *(const bf16x8*)(w1e + ((size_t)(kf * 24 + wid * 3 + jn)) * 1024 + lane * 16);
    };
    auto ldB4 = [&](int kf, int jn) {
        return *(const bf16x8*)(w4e + ((size_t)(kf * 48 + wid * 6 + jn)) * 1024 + lane * 16);
    };

    // ---- stage embA: fp32 -> bf16, swizzled [32][768] (non-temporal src) -
#pragma unroll
    for (int it = 0; it < 6; ++it) {
        int q   = threadIdx.x + it * 512;   // 0..3071 chunks of 8 k
        int row = q / 96, kq = q % 96;
        const float* s = emb + (size_t)ridxL[row] * D_DIM + kq * 8;
        f32x4 f0 = __builtin_nontemporal_load((const f32x4*)s);
        f32x4 f1 = __builtin_nontemporal_load((const f32x4*)(s + 4));
        bf16x8 p;
        p[0]=(bf16_t)f0[0]; p[1]=(bf16_t)f0[1]; p[2]=(bf16_t)f0[2]; p[3]=(bf16_t)f0[3];
        p[4]=(bf16_t)f1[0]; p[5]=(bf16_t)f1[1]; p[6]=(bf16_t)f1[2]; p[7]=(bf16_t)f1[3];
        *(bf16x8*)(smem + row * 1536 + ((kq * 16) ^ ((row & 7) << 4))) = p;
    }
    __syncthreads();   // (2) embA visible

    // ---------------- stage 1: h = relu(emb @ w1 + b1)  [32x384] ----------
    f32x4 acc1[2][3];
#pragma unroll
    for (int rg = 0; rg < 2; ++rg)
#pragma unroll
        for (int j = 0; j < 3; ++j) acc1[rg][j] = f32x4{0.f, 0.f, 0.f, 0.f};

    {
        bf16x8 B1buf[4][3];
#pragma unroll
        for (int p = 0; p < 4; ++p)
#pragma unroll
            for (int j = 0; j < 3; ++j) B1buf[p][j] = ldB1(p, j);

#pragma unroll
        for (int kf = 0; kf < 24; ++kf) {
            const int s = kf & 3;             // constant after unroll
            int kb = (kf * 32 + l4 * 8) * 2;
            bf16x8 a0 = *(const bf16x8*)(smem + l15 * 1536 + (kb ^ ((l15 & 7) << 4)));
            bf16x8 a1 = *(const bf16x8*)(smem + (l15 + 16) * 1536 + (kb ^ ((l15 & 7) << 4)));
            acc1[0][0] = mfma16(a0, B1buf[s][0], acc1[0][0]);
            acc1[1][0] = mfma16(a1, B1buf[s][0], acc1[1][0]);
            acc1[0][1] = mfma16(a0, B1buf[s][1], acc1[0][1]);
            acc1[1][1] = mfma16(a1, B1buf[s][1], acc1[1][1]);
            acc1[0][2] = mfma16(a0, B1buf[s][2], acc1[0][2]);
            acc1[1][2] = mfma16(a1, B1buf[s][2], acc1[1][2]);
            if (kf + 4 < 24) {
                B1buf[s][0] = ldB1(kf + 4, 0);
                B1buf[s][1] = ldB1(kf + 4, 1);
                B1buf[s][2] = ldB1(kf + 4, 2);
            }
            __builtin_amdgcn_sched_barrier(0);   // iteration fence
        }
    }
    __syncthreads();   // (3) all embA reads done; region reusable for h

    // h = relu(acc1 + b1) -> bf16 swizzled LDS @ 0 (stride 768)
#pragma unroll
    for (int jn = 0; jn < 3; ++jn) {
        int col = wid * 48 + jn * 16 + l15;
        float bb = b1[e * H_DIM + col];
#pragma unroll
        for (int rg = 0; rg < 2; ++rg)
#pragma unroll
            for (int v = 0; v < 4; ++v) {
                int row = rg * 16 + l4 * 4 + v;
                float hv = fmaxf(acc1[rg][jn][v] + bb, 0.f);
                *(bf16_t*)(smem + row * 768 + ((col * 2) ^ ((row & 7) << 4))) = (bf16_t)hv;
            }
    }
    __syncthreads();   // (4) h visible

    // ---------------- stage 2: eo = h @ w4  [32x768] ----------------------
    f32x4 acc2[2][6];
#pragma unroll
    for (int rg = 0; rg < 2; ++rg)
#pragma unroll
        for (int j = 0; j < 6; ++j) acc2[rg][j] = f32x4{0.f, 0.f, 0.f, 0.f};

    {
        bf16x8 B4buf[3][6];
#pragma unroll
        for (int p = 0; p < 3; ++p)
#pragma unroll
            for (int j = 0; j < 6; ++j) B4buf[p][j] = ldB4(p, j);

#pragma unroll
        for (int kf = 0; kf < 12; ++kf) {
            const int s = kf % 3;             // constant after unroll
            int kb = (kf * 32 + l4 * 8) * 2;
            bf16x8 a0 = *(const bf16x8*)(smem + l15 * 768 + (kb ^ ((l15 & 7) << 4)));
            bf16x8 a1 = *(const bf16x8*)(smem + (l15 + 16) * 768 + (kb ^ ((l15 & 7) << 4)));
            acc2[0][0] = mfma16(a0, B4buf[s][0], acc2[0][0]);
            acc2[1][0] = mfma16(a1, B4buf[s][0], acc2[1][0]);
            acc2[0][1] = mfma16(a0, B4buf[s][1], acc2[0][1]);
            acc2[1][1] = mfma16(a1, B4buf[s][1], acc2[1][1]);
            acc2[0][2] = mfma16(a0, B4buf[s][2], acc2[0][2]);
            acc2[1][2] = mfma16(a1, B4buf[s][2], acc2[1][2]);
            acc2[0][3] = mfma16(a0, B4buf[s][3], acc2[0][3]);
            acc2[1][3] = mfma16(a1, B4buf[s][3], acc2[1][3]);
            acc2[0][4] = mfma16(a0, B4buf[s][4], acc2[0][4]);
            acc2[1][4] = mfma16(a1, B4buf[s][4], acc2[1][4]);
            acc2[0][5] = mfma16(a0, B4buf[s][5], acc2[0][5]);
            acc2[1][5] = mfma16(a1, B4buf[s][5], acc2[1][5]);
            if (kf + 3 < 12) {
                B4buf[s][0] = ldB4(kf + 3, 0);
                B4buf[s][1] = ldB4(kf + 3, 1);
                B4buf[s][2] = ldB4(kf + 3, 2);
                B4buf[s][3] = ldB4(kf + 3, 3);
                B4buf[s][4] = ldB4(kf + 3, 4);
                B4buf[s][5] = ldB4(kf + 3, 5);
            }
            __builtin_amdgcn_sched_barrier(0);   // iteration fence
        }
    }

    // ---------------- epilogue: gate, l2norm, +emb, l2norm, scatter -------
    const int colb = wid * 96;
    float part[2][4];
#pragma unroll
    for (int rg = 0; rg < 2; ++rg)
#pragma unroll
        for (int v = 0; v < 4; ++v) part[rg][v] = 0.f;

#pragma unroll
    for (int jn = 0; jn < 6; ++jn) {
        float bb = b4[e * D_DIM + colb + jn * 16 + l15];
#pragma unroll
        for (int rg = 0; rg < 2; ++rg)
#pragma unroll
            for (int v = 0; v < 4; ++v) {
                float cv = (acc2[rg][jn][v] + bb) * gateL[rg * 16 + l4 * 4 + v];
                acc2[rg][jn][v] = cv;
                part[rg][v] += cv * cv;
            }
    }
#pragma unroll
    for (int o = 1; o < 16; o <<= 1)
#pragma unroll
        for (int rg = 0; rg < 2; ++rg)
#pragma unroll
            for (int v = 0; v < 4; ++v) part[rg][v] += __shfl_xor(part[rg][v], o, 64);
    if (l15 == 0)
#pragma unroll
        for (int rg = 0; rg < 2; ++rg)
#pragma unroll
            for (int v = 0; v < 4; ++v) ssb1[(rg * 16 + l4 * 4 + v) * 8 + wid] = part[rg][v];
    __syncthreads();   // (5) ssb1 ready

    int   rofs[2][4];   // ridx * D_DIM (int: max ~12.6M, fits)
    float inv1[2][4];
#pragma unroll
    for (int rg = 0; rg < 2; ++rg)
#pragma unroll
        for (int v = 0; v < 4; ++v) {
            int row = rg * 16 + l4 * 4 + v;
            rofs[rg][v] = ridxL[row] * D_DIM;
            float s = 0.f;
#pragma unroll
            for (int w = 0; w < 8; ++w) s += ssb1[row * 8 + w];
            inv1[rg][v] = 1.0f / fmaxf(sqrtf(s), 1e-6f);
        }

    float part2[2][4];
#pragma unroll
    for (int rg = 0; rg < 2; ++rg)
#pragma unroll
        for (int v = 0; v < 4; ++v) part2[rg][v] = 0.f;

#pragma unroll
    for (int jn = 0; jn < 6; ++jn) {
        int col = colb + jn * 16 + l15;
#pragma unroll
        for (int rg = 0; rg < 2; ++rg)
#pragma unroll
            for (int v = 0; v < 4; ++v) {
                float em = __builtin_nontemporal_load(emb + rofs[rg][v] + col);
                float o2 = acc2[rg][jn][v] * inv1[rg][v] + em;
                acc2[rg][jn][v] = o2;
                part2[rg][v] += o2 * o2;
            }
    }
#pragma unroll
    for (int o = 1; o < 16; o <<= 1)
#pragma unroll
        for (int rg = 0; rg < 2; ++rg)
#pragma unroll
            for (int v = 0; v < 4; ++v) part2[rg][v] += __shfl_xor(part2[rg][v], o, 64);
    if (l15 == 0)
#pragma unroll
        for (int rg = 0; rg < 2; ++rg)
#pragma unroll
            for (int v = 0; v < 4; ++v) ssb2[(rg * 16 + l4 * 4 + v) * 8 + wid] = part2[rg][v];
    __syncthreads();   // (6) ssb2 ready

#pragma unroll
    for (int rg = 0; rg < 2; ++rg)
#pragma unroll
        for (int v = 0; v < 4; ++v) {
            int row = rg * 16 + l4 * 4 + v;
            float s = 0.f;
#pragma unroll
            for (int w = 0; w < 8; ++w) s += ssb2[row * 8 + w];
            float inv2 = 1.0f / fmaxf(sqrtf(s), 1e-12f);
            if (row < Meff) {
#pragma unroll
                for (int jn = 0; jn < 6; ++jn)
                    __builtin_nontemporal_store(acc2[rg][jn][v] * inv2,
                                                out + rofs[rg][v] + colb + jn * 16 + l15);
            }
        }
}

// ---------------------------------------------------------------------------
extern "C" void kernel_launch(void* const* d_in, const int* in_sizes, int n_in,
                              void* d_out, int out_size, void* d_ws, size_t ws_size,
                              hipStream_t stream) {
    const float* emb    = (const float*)d_in[0];
    const float* logits = (const float*)d_in[1];
    const float* w1     = (const float*)d_in[2];
    const float* b1     = (const float*)d_in[3];
    const float* w4     = (const float*)d_in[4];
    const float* b4     = (const float*)d_in[5];
    float* out = (float*)d_out;
    char*  ws  = (char*)d_ws;
    if (ws_size < WS_END) return;  // workspace too small -> fail loudly

    int*   cnt     = (int*)(ws + WS_CNT);
    int*   cur     = (int*)(ws + WS_CUR);
    int*   offs    = (int*)(ws + WS_OFF);
    int*   toff    = (int*)(ws + WS_TOFF);
    int*   expert  = (int*)(ws + WS_EXP);
    float* gatev   = (float*)(ws + WS_GATE);
    int*   rowlist = (int*)(ws + WS_ROW);
    char*  w1s     = ws + WS_W1;
    char*  w4s     = ws + WS_W4;

    hipMemsetAsync(ws, 0, 512, stream);
    // weights convert (2304 blocks) + gate (32 blocks) in one dispatch
    prep<<<dim3(2336), dim3(512), 0, stream>>>(w1, w4, logits, w1s, w4s,
                                               expert, gatev, cnt);
    scank<<<dim3(1), dim3(64), 0, stream>>>(cnt, offs, toff);
    scatk<<<dim3(32), dim3(512), 0, stream>>>(expert, offs, cur, rowlist);

    (void)hipFuncSetAttribute((const void*)moe_main,
                              hipFuncAttributeMaxDynamicSharedMemorySize, SMEM_BYTES);
    // max tiles = sum_e ceil(cnt_e/32) <= 527; grid 528 = 8*66 (swizzle)
    moe_main<<<dim3(528), dim3(512), SMEM_BYTES, stream>>>(
        emb, gatev, rowlist, cnt, offs, toff, w1s, w4s, b1, b4, out);
}

// Round 9
// 109.991 us; speedup vs baseline: 1.4914x; 1.3255x over previous
//
#include <hip/hip_runtime.h>
#include <stdint.h>

// ---------------------------------------------------------------------------
// MoEBiEncoder: top-1 MoE (C=16 experts), per-row 768 -> relu(384) -> 768,
// gate-scale, l2norm, +residual, l2norm.  B=16384, D=768, H=384.
//
// v9: R5 structure (32-row tiles, A in LDS, B streamed from L2), with
//     ROLLED K-loops (#pragma unroll 2, pointer-increment addressing).
//     Theory: fully-unrolled ~16KB straight-line bodies were streamed from
//     L2 by every wave with zero I$ reuse (~50k cy/block) - the invariant
//     cost across R2-R8 that no data-side tweak moved. All non-temporal
//     accesses reverted (R8: they bypassed L2 -> FETCH+WRITE explosion).
// ---------------------------------------------------------------------------

#define B_ROWS 16384
#define C_EXP  16
#define D_DIM  768
#define H_DIM  384

typedef __bf16 bf16_t;
typedef __bf16 bf16x8 __attribute__((ext_vector_type(8)));
typedef float  f32x4  __attribute__((ext_vector_type(4)));

// ---- workspace layout (bytes) ----
static constexpr size_t WS_CNT  = 0;                       // 16 int
static constexpr size_t WS_CUR  = 64;                      // 16 int
static constexpr size_t WS_OFF  = 128;                     // 17 int
static constexpr size_t WS_TOFF = 256;                     // 17 int
static constexpr size_t WS_EXP  = 512;                     // B int
static constexpr size_t WS_GATE = WS_EXP  + (size_t)B_ROWS * 4;
static constexpr size_t WS_ROW  = WS_GATE + (size_t)B_ROWS * 4;
static constexpr size_t WS_W1   = WS_ROW  + (size_t)B_ROWS * 4;
static constexpr size_t W_BYTES = (size_t)C_EXP * D_DIM * H_DIM * 2;  // 9437184
static constexpr size_t WS_W4   = WS_W1 + W_BYTES;
static constexpr size_t WS_END  = WS_W4 + W_BYTES;         // ~18.2 MB

// Fragment-major weight layout (per expert, KF = K/32, NF = N/16):
//   frag(kf,nf) = 1024 contiguous bytes; lane l's 16B at l*16 hold
//   w[k0 + (l>>4)*8 + j][n0 + (l&15)], j=0..7.
// w1: KF=24, NF=24.  w4: KF=12, NF=48.

__device__ __forceinline__ f32x4 mfma16(bf16x8 a, bf16x8 b, f32x4 c) {
    return __builtin_amdgcn_mfma_f32_16x16x32_bf16(a, b, c, 0, 0, 0);
}

// ---------------------------------------------------------------------------
// Kernel 1 "prep": blocks 0..2303 convert weights; blocks 2304..2335 do the
// gate (softmax/argmax) + per-expert counts via LDS histogram.
// ---------------------------------------------------------------------------
__global__ __launch_bounds__(512) void prep(const float* __restrict__ w1,
                                            const float* __restrict__ w4,
                                            const float* __restrict__ logits,
                                            char* __restrict__ w1s,
                                            char* __restrict__ w4s,
                                            int* __restrict__ expert,
                                            float* __restrict__ gatev,
                                            int* __restrict__ cnt) {
    __shared__ float tile[64 * 65];
    __shared__ int   hist[16];
    int bid = blockIdx.x;

    if (bid >= 2304) {
        // ---------------- gate part: 32 blocks x 512 threads --------------
        if (threadIdx.x < 16) hist[threadIdx.x] = 0;
        __syncthreads();
        int b = (bid - 2304) * 512 + threadIdx.x;   // 0..16383
        const f32x4* lp = (const f32x4*)(logits + (size_t)b * C_EXP);
        float l[16];
#pragma unroll
        for (int i = 0; i < 4; ++i) {
            f32x4 v = lp[i];
            l[i*4+0] = v[0]; l[i*4+1] = v[1]; l[i*4+2] = v[2]; l[i*4+3] = v[3];
        }
        float m = l[0]; int idx = 0;
#pragma unroll
        for (int j = 1; j < 16; ++j)
            if (l[j] > m) { m = l[j]; idx = j; }   // first-max == np.argmax
        float s = 0.f;
#pragma unroll
        for (int j = 0; j < 16; ++j) s += __expf((l[j] - m) * 0.1f);
        expert[b] = idx;
        gatev[b]  = 1.0f / s;          // softmax value at the argmax
        atomicAdd(&hist[idx], 1);      // LDS atomic (fast)
        __syncthreads();
        if (threadIdx.x < 16) {
            int c = hist[threadIdx.x];
            if (c) atomicAdd(&cnt[threadIdx.x], c);   // <=16 global atomics/blk
        }
        return;
    }

    // ---------------- weight convert: fp32 [K][N] -> bf16 fragment-major --
    bool is1 = bid < 1152;
    int lb = is1 ? bid : bid - 1152;
    int c = lb / 72, rem = lb % 72;
    int kc, nb, Nfull, KF, NF;
    const float* src;
    char* dstbase;
    if (is1) {
        kc = rem / 6;  nb = rem % 6;  Nfull = H_DIM; KF = 24; NF = 24;
        src     = w1 + (size_t)c * D_DIM * H_DIM;
        dstbase = w1s;
    } else {
        kc = rem / 12; nb = rem % 12; Nfull = D_DIM; KF = 12; NF = 48;
        src     = w4 + (size_t)c * H_DIM * D_DIM;
        dstbase = w4s;
    }
    // read 64(k) x 64(n) fp32 tile, coalesced along n
#pragma unroll
    for (int it = 0; it < 2; ++it) {
        int f  = threadIdx.x + it * 512;   // float4 id 0..1023
        int kr = f >> 4, nq = f & 15;
        f32x4 v = *(const f32x4*)(src + (size_t)(kc * 64 + kr) * Nfull + nb * 64 + nq * 4);
        tile[kr * 65 + nq * 4 + 0] = v[0];
        tile[kr * 65 + nq * 4 + 1] = v[1];
        tile[kr * 65 + nq * 4 + 2] = v[2];
        tile[kr * 65 + nq * 4 + 3] = v[3];
    }
    __syncthreads();
    // write 8 fragments (one per 64-thread group), 16B/lane coalesced
    {
        int frag = threadIdx.x >> 6, lane = threadIdx.x & 63;
        int kfl  = frag >> 2, nfl = frag & 3;
        int col  = lane & 15, kq = lane >> 4;
        bf16x8 p;
#pragma unroll
        for (int j = 0; j < 8; ++j)
            p[j] = (bf16_t)tile[(kfl * 32 + kq * 8 + j) * 65 + nfl * 16 + col];
        int kf = kc * 2 + kfl, nf = nb * 4 + nfl;
        size_t off = (((size_t)c * KF + kf) * NF + nf) * 1024 + lane * 16;
        *(bf16x8*)(dstbase + off) = p;
    }
}

// ---------------------------------------------------------------------------
// Kernel 2: tiny serial scan (16 experts), 32-row tiles.
// ---------------------------------------------------------------------------
__global__ void scank(const int* __restrict__ cnt, int* __restrict__ offs,
                      int* __restrict__ toff) {
    if (threadIdx.x == 0 && blockIdx.x == 0) {
        int o = 0, to = 0;
        for (int e = 0; e < C_EXP; ++e) {
            offs[e] = o; toff[e] = to;
            o  += cnt[e];
            to += (cnt[e] + 31) >> 5;
        }
        offs[C_EXP] = o; toff[C_EXP] = to;
    }
}

// ---------------------------------------------------------------------------
// Kernel 3: bucket rows by expert (hierarchical: LDS rank + 16 atomics/blk).
// ---------------------------------------------------------------------------
__global__ __launch_bounds__(512) void scatk(const int* __restrict__ expert,
                                             const int* __restrict__ offs,
                                             int* __restrict__ cursor,
                                             int* __restrict__ rowlist) {
    __shared__ int lcur[16], lbase[16];
    int b = blockIdx.x * 512 + threadIdx.x;   // grid 32 -> 0..16383
    if (threadIdx.x < 16) lcur[threadIdx.x] = 0;
    __syncthreads();
    int e = expert[b];
    int p = atomicAdd(&lcur[e], 1);           // LDS atomic
    __syncthreads();
    if (threadIdx.x < 16) {
        int c = lcur[threadIdx.x];
        lbase[threadIdx.x] = c ? atomicAdd(&cursor[threadIdx.x], c) : 0;
    }
    __syncthreads();
    rowlist[offs[e] + lbase[e] + p] = b;
}

// ---------------------------------------------------------------------------
// Kernel 4: grouped GEMM + fused epilogue.
// One block = 32 rows of one expert, 512 threads = 8 waves (N-split).
// LDS (51456 B):
//   [0, 49152)  embA [32][768] bf16 swz (stage 1)
//   [0, 24576)  h    [32][384] bf16 swz (stage 2; aliases dead embA)
//   ssb1 @49152 (1 KB); ssb2 @50176 (1 KB); ridx @51200; gate @51328.
// K-loops ROLLED (#pragma unroll 2): ~50-instruction bodies that stay hot
// in I$ instead of ~16KB of streamed straight-line code.
// ---------------------------------------------------------------------------
#define SMEM_BYTES 51456

__global__ __launch_bounds__(512, 4) void moe_main(
    const float* __restrict__ emb, const float* __restrict__ gatev,
    const int* __restrict__ rowlist, const int* __restrict__ cnt,
    const int* __restrict__ offs, const int* __restrict__ toff,
    const char* __restrict__ w1s, const char* __restrict__ w4s,
    const float* __restrict__ b1, const float* __restrict__ b4,
    float* __restrict__ out) {
    extern __shared__ char smem[];

    // XCD-aware bijective swizzle: grid 528 = 8 * 66
    int bid = blockIdx.x;
    int t   = (bid & 7) * 66 + (bid >> 3);

    int total = toff[C_EXP];
    if (t >= total) return;
    int e = 0;
#pragma unroll
    for (int i = 1; i < C_EXP; ++i) e = (t >= toff[i]) ? i : e;
    int tin  = t - toff[e];
    int Meff = cnt[e] - tin * 32; if (Meff > 32) Meff = 32;
    int base = offs[e] + tin * 32;

    float* ssb1  = (float*)(smem + 49152);   // [32][8]
    float* ssb2  = (float*)(smem + 50176);   // [32][8]
    int*   ridxL = (int*)(smem + 51200);
    float* gateL = (float*)(smem + 51328);
    if (threadIdx.x < 32) {
        int rr = threadIdx.x;
        int p  = base + (rr < Meff ? rr : 0);   // clamp pad rows
        int ri = rowlist[p];
        ridxL[rr] = ri;
        gateL[rr] = gatev[ri];
    }
    __syncthreads();   // (1) ridxL visible

    const int wid  = threadIdx.x >> 6;
    const int lane = threadIdx.x & 63;
    const int l15  = lane & 15, l4 = lane >> 4;
    const int sw   = (l15 & 7) << 4;          // A-read XOR swizzle term

    const char* w1e = w1s + (size_t)e * 589824;
    const char* w4e = w4s + (size_t)e * 589824;

    // ---- stage embA: fp32 -> bf16, swizzled [32][768] (rolled) -----------
    {
        int row = threadIdx.x / 96, kq = threadIdx.x % 96;   // 512 thr
        // 6 chunks of 512: rows advance by 512/96 pattern; recompute per it
#pragma unroll 2
        for (int it = 0; it < 6; ++it) {
            int q = threadIdx.x + it * 512;
            int r = q / 96, k = q % 96;
            const float* s = emb + (size_t)ridxL[r] * D_DIM + k * 8;
            f32x4 f0 = *(const f32x4*)s;
            f32x4 f1 = *(const f32x4*)(s + 4);
            bf16x8 p;
            p[0]=(bf16_t)f0[0]; p[1]=(bf16_t)f0[1]; p[2]=(bf16_t)f0[2]; p[3]=(bf16_t)f0[3];
            p[4]=(bf16_t)f1[0]; p[5]=(bf16_t)f1[1]; p[6]=(bf16_t)f1[2]; p[7]=(bf16_t)f1[3];
            *(bf16x8*)(smem + r * 1536 + ((k * 16) ^ ((r & 7) << 4))) = p;
        }
        (void)row; (void)kq;
    }
    __syncthreads();   // (2) embA visible

    // ---------------- stage 1: h = relu(emb @ w1 + b1)  [32x384] ----------
    f32x4 acc1[2][3];
#pragma unroll
    for (int rg = 0; rg < 2; ++rg)
#pragma unroll
        for (int j = 0; j < 3; ++j) acc1[rg][j] = f32x4{0.f, 0.f, 0.f, 0.f};

    {
        const char* w1p = w1e + (wid * 3) * 1024 + lane * 16;
        const char* aB  = smem + l15 * 1536;
        const char* aB2 = smem + (l15 + 16) * 1536;
        int kb = l4 * 16;
#pragma unroll 2
        for (int kf = 0; kf < 24; ++kf) {
            bf16x8 a0 = *(const bf16x8*)(aB  + (kb ^ sw));
            bf16x8 a1 = *(const bf16x8*)(aB2 + (kb ^ sw));
            bf16x8 b0 = *(const bf16x8*)(w1p);
            bf16x8 bv1 = *(const bf16x8*)(w1p + 1024);
            bf16x8 bv2 = *(const bf16x8*)(w1p + 2048);
            acc1[0][0] = mfma16(a0, b0,  acc1[0][0]);
            acc1[1][0] = mfma16(a1, b0,  acc1[1][0]);
            acc1[0][1] = mfma16(a0, bv1, acc1[0][1]);
            acc1[1][1] = mfma16(a1, bv1, acc1[1][1]);
            acc1[0][2] = mfma16(a0, bv2, acc1[0][2]);
            acc1[1][2] = mfma16(a1, bv2, acc1[1][2]);
            w1p += 24 * 1024;
            kb  += 64;
        }
    }
    __syncthreads();   // (3) all embA reads done; region reusable for h

    // h = relu(acc1 + b1) -> bf16 swizzled LDS @ 0 (stride 768)
#pragma unroll
    for (int jn = 0; jn < 3; ++jn) {
        int col = wid * 48 + jn * 16 + l15;
        float bb = b1[e * H_DIM + col];
#pragma unroll
        for (int rg = 0; rg < 2; ++rg)
#pragma unroll
            for (int v = 0; v < 4; ++v) {
                int row = rg * 16 + l4 * 4 + v;
                float hv = fmaxf(acc1[rg][jn][v] + bb, 0.f);
                *(bf16_t*)(smem + row * 768 + ((col * 2) ^ ((row & 7) << 4))) = (bf16_t)hv;
            }
    }
    __syncthreads();   // (4) h visible

    // ---------------- stage 2: eo = h @ w4  [32x768] ----------------------
    f32x4 acc2[2][6];
#pragma unroll
    for (int rg = 0; rg < 2; ++rg)
#pragma unroll
        for (int j = 0; j < 6; ++j) acc2[rg][j] = f32x4{0.f, 0.f, 0.f, 0.f};

    {
        const char* w4p = w4e + (wid * 6) * 1024 + lane * 16;
        const char* aB  = smem + l15 * 768;
        const char* aB2 = smem + (l15 + 16) * 768;
        int kb = l4 * 16;
#pragma unroll 2
        for (int kf = 0; kf < 12; ++kf) {
            bf16x8 a0 = *(const bf16x8*)(aB  + (kb ^ sw));
            bf16x8 a1 = *(const bf16x8*)(aB2 + (kb ^ sw));
            bf16x8 b0 = *(const bf16x8*)(w4p);
            bf16x8 bv1 = *(const bf16x8*)(w4p + 1024);
            bf16x8 bv2 = *(const bf16x8*)(w4p + 2048);
            bf16x8 bv3 = *(const bf16x8*)(w4p + 3072);
            bf16x8 bv4 = *(const bf16x8*)(w4p + 4096);
            bf16x8 bv5 = *(const bf16x8*)(w4p + 5120);
            acc2[0][0] = mfma16(a0, b0,  acc2[0][0]);
            acc2[1][0] = mfma16(a1, b0,  acc2[1][0]);
            acc2[0][1] = mfma16(a0, bv1, acc2[0][1]);
            acc2[1][1] = mfma16(a1, bv1, acc2[1][1]);
            acc2[0][2] = mfma16(a0, bv2, acc2[0][2]);
            acc2[1][2] = mfma16(a1, bv2, acc2[1][2]);
            acc2[0][3] = mfma16(a0, bv3, acc2[0][3]);
            acc2[1][3] = mfma16(a1, bv3, acc2[1][3]);
            acc2[0][4] = mfma16(a0, bv4, acc2[0][4]);
            acc2[1][4] = mfma16(a1, bv4, acc2[1][4]);
            acc2[0][5] = mfma16(a0, bv5, acc2[0][5]);
            acc2[1][5] = mfma16(a1, bv5, acc2[1][5]);
            w4p += 48 * 1024;
            kb  += 64;
        }
    }

    // ---------------- epilogue: gate, l2norm, +emb, l2norm, scatter -------
    const int colb = wid * 96;
    float part[2][4];
#pragma unroll
    for (int rg = 0; rg < 2; ++rg)
#pragma unroll
        for (int v = 0; v < 4; ++v) part[rg][v] = 0.f;

#pragma unroll
    for (int jn = 0; jn < 6; ++jn) {
        float bb = b4[e * D_DIM + colb + jn * 16 + l15];
#pragma unroll
        for (int rg = 0; rg < 2; ++rg)
#pragma unroll
            for (int v = 0; v < 4; ++v) {
                float cv = (acc2[rg][jn][v] + bb) * gateL[rg * 16 + l4 * 4 + v];
                acc2[rg][jn][v] = cv;
                part[rg][v] += cv * cv;
            }
    }
#pragma unroll
    for (int o = 1; o < 16; o <<= 1)
#pragma unroll
        for (int rg = 0; rg < 2; ++rg)
#pragma unroll
            for (int v = 0; v < 4; ++v) part[rg][v] += __shfl_xor(part[rg][v], o, 64);
    if (l15 == 0)
#pragma unroll
        for (int rg = 0; rg < 2; ++rg)
#pragma unroll
            for (int v = 0; v < 4; ++v) ssb1[(rg * 16 + l4 * 4 + v) * 8 + wid] = part[rg][v];
    __syncthreads();   // (5) ssb1 ready

    int   rofs[2][4];   // ridx * D_DIM (int: max ~12.6M, fits)
    float inv1[2][4];
#pragma unroll
    for (int rg = 0; rg < 2; ++rg)
#pragma unroll
        for (int v = 0; v < 4; ++v) {
            int row = rg * 16 + l4 * 4 + v;
            rofs[rg][v] = ridxL[row] * D_DIM;
            float s = 0.f;
#pragma unroll
            for (int w = 0; w < 8; ++w) s += ssb1[row * 8 + w];
            inv1[rg][v] = 1.0f / fmaxf(sqrtf(s), 1e-6f);
        }

    float part2[2][4];
#pragma unroll
    for (int rg = 0; rg < 2; ++rg)
#pragma unroll
        for (int v = 0; v < 4; ++v) part2[rg][v] = 0.f;

#pragma unroll
    for (int jn = 0; jn < 6; ++jn) {
        int col = colb + jn * 16 + l15;
#pragma unroll
        for (int rg = 0; rg < 2; ++rg)
#pragma unroll
            for (int v = 0; v < 4; ++v) {
                float em = emb[rofs[rg][v] + col];
                float o2 = acc2[rg][jn][v] * inv1[rg][v] + em;
                acc2[rg][jn][v] = o2;
                part2[rg][v] += o2 * o2;
            }
    }
#pragma unroll
    for (int o = 1; o < 16; o <<= 1)
#pragma unroll
        for (int rg = 0; rg < 2; ++rg)
#pragma unroll
            for (int v = 0; v < 4; ++v) part2[rg][v] += __shfl_xor(part2[rg][v], o, 64);
    if (l15 == 0)
#pragma unroll
        for (int rg = 0; rg < 2; ++rg)
#pragma unroll
            for (int v = 0; v < 4; ++v) ssb2[(rg * 16 + l4 * 4 + v) * 8 + wid] = part2[rg][v];
    __syncthreads();   // (6) ssb2 ready

#pragma unroll
    for (int rg = 0; rg < 2; ++rg)
#pragma unroll
        for (int v = 0; v < 4; ++v) {
            int row = rg * 16 + l4 * 4 + v;
            float s = 0.f;
#pragma unroll
            for (int w = 0; w < 8; ++w) s += ssb2[row * 8 + w];
            float inv2 = 1.0f / fmaxf(sqrtf(s), 1e-12f);
            if (row < Meff) {
#pragma unroll
                for (int jn = 0; jn < 6; ++jn)
                    out[rofs[rg][v] + colb + jn * 16 + l15] = acc2[rg][jn][v] * inv2;
            }
        }
}

// ---------------------------------------------------------------------------
extern "C" void kernel_launch(void* const* d_in, const int* in_sizes, int n_in,
                              void* d_out, int out_size, void* d_ws, size_t ws_size,
                              hipStream_t stream) {
    const float* emb    = (const float*)d_in[0];
    const float* logits = (const float*)d_in[1];
    const float* w1     = (const float*)d_in[2];
    const float* b1     = (const float*)d_in[3];
    const float* w4     = (const float*)d_in[4];
    const float* b4     = (const float*)d_in[5];
    float* out = (float*)d_out;
    char*  ws  = (char*)d_ws;
    if (ws_size < WS_END) return;  // workspace too small -> fail loudly

    int*   cnt     = (int*)(ws + WS_CNT);
    int*   cur     = (int*)(ws + WS_CUR);
    int*   offs    = (int*)(ws + WS_OFF);
    int*   toff    = (int*)(ws + WS_TOFF);
    int*   expert  = (int*)(ws + WS_EXP);
    float* gatev   = (float*)(ws + WS_GATE);
    int*   rowlist = (int*)(ws + WS_ROW);
    char*  w1s     = ws + WS_W1;
    char*  w4s     = ws + WS_W4;

    hipMemsetAsync(ws, 0, 512, stream);
    // weights convert (2304 blocks) + gate (32 blocks) in one dispatch
    prep<<<dim3(2336), dim3(512), 0, stream>>>(w1, w4, logits, w1s, w4s,
                                               expert, gatev, cnt);
    scank<<<dim3(1), dim3(64), 0, stream>>>(cnt, offs, toff);
    scatk<<<dim3(32), dim3(512), 0, stream>>>(expert, offs, cur, rowlist);

    (void)hipFuncSetAttribute((const void*)moe_main,
                              hipFuncAttributeMaxDynamicSharedMemorySize, SMEM_BYTES);
    // max tiles = sum_e ceil(cnt_e/32) <= 527; grid 528 = 8*66 (swizzle)
    moe_main<<<dim3(528), dim3(512), SMEM_BYTES, stream>>>(
        emb, gatev, rowlist, cnt, offs, toff, w1s, w4s, b1, b4, out);
}

// Round 10
// 97.453 us; speedup vs baseline: 1.6832x; 1.1287x over previous
//
#include <hip/hip_runtime.h>
#include <stdint.h>

// ---------------------------------------------------------------------------
// MoEBiEncoder: top-1 MoE (C=16 experts), per-row 768 -> relu(384) -> 768,
// gate-scale, l2norm, +residual, l2norm.  B=16384, D=768, H=384.
//
// v10: TLP play. TILE=16 rows -> 1040 blocks (4/CU available vs 2.06),
//      LDS 25.7 KB (6 blocks/CU fit), acc 12+24 f32 regs -> 3-4 resident
//      blocks/CU = 24-32 waves/CU overlap the per-block phase chains.
//      Explicit trade: weight L2 traffic doubles (~1.17 GB, ~34us L2 floor)
//      for 4x thread-level parallelism. Structure otherwise = R5 (best).
// ---------------------------------------------------------------------------

#define B_ROWS 16384
#define C_EXP  16
#define D_DIM  768
#define H_DIM  384

typedef __bf16 bf16_t;
typedef __bf16 bf16x8 __attribute__((ext_vector_type(8)));
typedef float  f32x4  __attribute__((ext_vector_type(4)));

// ---- workspace layout (bytes) ----
static constexpr size_t WS_CNT  = 0;                       // 16 int
static constexpr size_t WS_CUR  = 64;                      // 16 int
static constexpr size_t WS_OFF  = 128;                     // 17 int
static constexpr size_t WS_TOFF = 256;                     // 17 int
static constexpr size_t WS_EXP  = 512;                     // B int
static constexpr size_t WS_GATE = WS_EXP  + (size_t)B_ROWS * 4;
static constexpr size_t WS_ROW  = WS_GATE + (size_t)B_ROWS * 4;
static constexpr size_t WS_W1   = WS_ROW  + (size_t)B_ROWS * 4;
static constexpr size_t W_BYTES = (size_t)C_EXP * D_DIM * H_DIM * 2;  // 9437184
static constexpr size_t WS_W4   = WS_W1 + W_BYTES;
static constexpr size_t WS_END  = WS_W4 + W_BYTES;         // ~18.2 MB

// Fragment-major weight layout (per expert, KF = K/32, NF = N/16):
//   frag(kf,nf) = 1024 contiguous bytes; lane l's 16B at l*16 hold
//   w[k0 + (l>>4)*8 + j][n0 + (l&15)], j=0..7.
// w1: KF=24, NF=24.  w4: KF=12, NF=48.

__device__ __forceinline__ f32x4 mfma16(bf16x8 a, bf16x8 b, f32x4 c) {
    return __builtin_amdgcn_mfma_f32_16x16x32_bf16(a, b, c, 0, 0, 0);
}

// ---------------------------------------------------------------------------
// Kernel 1 "prep": blocks 0..2303 convert weights; blocks 2304..2335 do the
// gate (softmax/argmax) + per-expert counts via LDS histogram.
// ---------------------------------------------------------------------------
__global__ __launch_bounds__(512) void prep(const float* __restrict__ w1,
                                            const float* __restrict__ w4,
                                            const float* __restrict__ logits,
                                            char* __restrict__ w1s,
                                            char* __restrict__ w4s,
                                            int* __restrict__ expert,
                                            float* __restrict__ gatev,
                                            int* __restrict__ cnt) {
    __shared__ float tile[64 * 65];
    __shared__ int   hist[16];
    int bid = blockIdx.x;

    if (bid >= 2304) {
        // ---------------- gate part: 32 blocks x 512 threads --------------
        if (threadIdx.x < 16) hist[threadIdx.x] = 0;
        __syncthreads();
        int b = (bid - 2304) * 512 + threadIdx.x;   // 0..16383
        const f32x4* lp = (const f32x4*)(logits + (size_t)b * C_EXP);
        float l[16];
#pragma unroll
        for (int i = 0; i < 4; ++i) {
            f32x4 v = lp[i];
            l[i*4+0] = v[0]; l[i*4+1] = v[1]; l[i*4+2] = v[2]; l[i*4+3] = v[3];
        }
        float m = l[0]; int idx = 0;
#pragma unroll
        for (int j = 1; j < 16; ++j)
            if (l[j] > m) { m = l[j]; idx = j; }   // first-max == np.argmax
        float s = 0.f;
#pragma unroll
        for (int j = 0; j < 16; ++j) s += __expf((l[j] - m) * 0.1f);
        expert[b] = idx;
        gatev[b]  = 1.0f / s;          // softmax value at the argmax
        atomicAdd(&hist[idx], 1);      // LDS atomic (fast)
        __syncthreads();
        if (threadIdx.x < 16) {
            int c = hist[threadIdx.x];
            if (c) atomicAdd(&cnt[threadIdx.x], c);   // <=16 global atomics/blk
        }
        return;
    }

    // ---------------- weight convert: fp32 [K][N] -> bf16 fragment-major --
    bool is1 = bid < 1152;
    int lb = is1 ? bid : bid - 1152;
    int c = lb / 72, rem = lb % 72;
    int kc, nb, Nfull, KF, NF;
    const float* src;
    char* dstbase;
    if (is1) {
        kc = rem / 6;  nb = rem % 6;  Nfull = H_DIM; KF = 24; NF = 24;
        src     = w1 + (size_t)c * D_DIM * H_DIM;
        dstbase = w1s;
    } else {
        kc = rem / 12; nb = rem % 12; Nfull = D_DIM; KF = 12; NF = 48;
        src     = w4 + (size_t)c * H_DIM * D_DIM;
        dstbase = w4s;
    }
    // read 64(k) x 64(n) fp32 tile, coalesced along n
#pragma unroll
    for (int it = 0; it < 2; ++it) {
        int f  = threadIdx.x + it * 512;   // float4 id 0..1023
        int kr = f >> 4, nq = f & 15;
        f32x4 v = *(const f32x4*)(src + (size_t)(kc * 64 + kr) * Nfull + nb * 64 + nq * 4);
        tile[kr * 65 + nq * 4 + 0] = v[0];
        tile[kr * 65 + nq * 4 + 1] = v[1];
        tile[kr * 65 + nq * 4 + 2] = v[2];
        tile[kr * 65 + nq * 4 + 3] = v[3];
    }
    __syncthreads();
    // write 8 fragments (one per 64-thread group), 16B/lane coalesced
    {
        int frag = threadIdx.x >> 6, lane = threadIdx.x & 63;
        int kfl  = frag >> 2, nfl = frag & 3;
        int col  = lane & 15, kq = lane >> 4;
        bf16x8 p;
#pragma unroll
        for (int j = 0; j < 8; ++j)
            p[j] = (bf16_t)tile[(kfl * 32 + kq * 8 + j) * 65 + nfl * 16 + col];
        int kf = kc * 2 + kfl, nf = nb * 4 + nfl;
        size_t off = (((size_t)c * KF + kf) * NF + nf) * 1024 + lane * 16;
        *(bf16x8*)(dstbase + off) = p;
    }
}

// ---------------------------------------------------------------------------
// Kernel 2: tiny serial scan (16 experts), 16-row tiles.
// ---------------------------------------------------------------------------
__global__ void scank(const int* __restrict__ cnt, int* __restrict__ offs,
                      int* __restrict__ toff) {
    if (threadIdx.x == 0 && blockIdx.x == 0) {
        int o = 0, to = 0;
        for (int e = 0; e < C_EXP; ++e) {
            offs[e] = o; toff[e] = to;
            o  += cnt[e];
            to += (cnt[e] + 15) >> 4;
        }
        offs[C_EXP] = o; toff[C_EXP] = to;
    }
}

// ---------------------------------------------------------------------------
// Kernel 3: bucket rows by expert (hierarchical: LDS rank + 16 atomics/blk).
// ---------------------------------------------------------------------------
__global__ __launch_bounds__(512) void scatk(const int* __restrict__ expert,
                                             const int* __restrict__ offs,
                                             int* __restrict__ cursor,
                                             int* __restrict__ rowlist) {
    __shared__ int lcur[16], lbase[16];
    int b = blockIdx.x * 512 + threadIdx.x;   // grid 32 -> 0..16383
    if (threadIdx.x < 16) lcur[threadIdx.x] = 0;
    __syncthreads();
    int e = expert[b];
    int p = atomicAdd(&lcur[e], 1);           // LDS atomic
    __syncthreads();
    if (threadIdx.x < 16) {
        int c = lcur[threadIdx.x];
        lbase[threadIdx.x] = c ? atomicAdd(&cursor[threadIdx.x], c) : 0;
    }
    __syncthreads();
    rowlist[offs[e] + lbase[e] + p] = b;
}

// ---------------------------------------------------------------------------
// Kernel 4: grouped GEMM + fused epilogue.
// One block = 16 rows of one expert, 512 threads = 8 waves (pure N-split):
//   stage1: wave w owns h cols [w*48, w*48+48)  (3 frags)
//   stage2: wave w owns out cols [w*96, w*96+96) (6 frags)
// LDS (25728 B):
//   [0, 24576)  embA [16][768] bf16 swz (stage 1)
//   [0, 12288)  h    [16][384] bf16 swz (stage 2; aliases dead embA)
//   ssb1 @24576 (512B); ssb2 @25088 (512B); ridx @25600; gate @25664.
// Small acc (12+24 f32) + small LDS -> 3-4 resident blocks/CU at grid 1040.
// ---------------------------------------------------------------------------
#define SMEM_BYTES 25728

__global__ __launch_bounds__(512) void moe_main(
    const float* __restrict__ emb, const float* __restrict__ gatev,
    const int* __restrict__ rowlist, const int* __restrict__ cnt,
    const int* __restrict__ offs, const int* __restrict__ toff,
    const char* __restrict__ w1s, const char* __restrict__ w4s,
    const float* __restrict__ b1, const float* __restrict__ b4,
    float* __restrict__ out) {
    extern __shared__ char smem[];

    // XCD-aware bijective swizzle: grid 1040 = 8 * 130
    int bid = blockIdx.x;
    int t   = (bid & 7) * 130 + (bid >> 3);

    int total = toff[C_EXP];
    if (t >= total) return;
    int e = 0;
#pragma unroll
    for (int i = 1; i < C_EXP; ++i) e = (t >= toff[i]) ? i : e;
    int tin  = t - toff[e];
    int Meff = cnt[e] - tin * 16; if (Meff > 16) Meff = 16;
    int base = offs[e] + tin * 16;

    float* ssb1  = (float*)(smem + 24576);   // [16][8]
    float* ssb2  = (float*)(smem + 25088);   // [16][8]
    int*   ridxL = (int*)(smem + 25600);
    float* gateL = (float*)(smem + 25664);
    if (threadIdx.x < 16) {
        int rr = threadIdx.x;
        int p  = base + (rr < Meff ? rr : 0);   // clamp pad rows
        int ri = rowlist[p];
        ridxL[rr] = ri;
        gateL[rr] = gatev[ri];
    }
    __syncthreads();   // (1) ridxL visible

    const int wid  = threadIdx.x >> 6;
    const int lane = threadIdx.x & 63;
    const int l15  = lane & 15, l4 = lane >> 4;

    const char* w1e = w1s + (size_t)e * 589824;
    const char* w4e = w4s + (size_t)e * 589824;

    // ---- stage embA: fp32 -> bf16, swizzled [16][768] --------------------
    // 16 rows x 96 8-elt chunks = 1536 chunks / 512 threads = 3 iters
#pragma unroll
    for (int it = 0; it < 3; ++it) {
        int q   = threadIdx.x + it * 512;
        int row = q / 96, kq = q % 96;
        const float* s = emb + (size_t)ridxL[row] * D_DIM + kq * 8;
        f32x4 f0 = *(const f32x4*)s;
        f32x4 f1 = *(const f32x4*)(s + 4);
        bf16x8 p;
        p[0]=(bf16_t)f0[0]; p[1]=(bf16_t)f0[1]; p[2]=(bf16_t)f0[2]; p[3]=(bf16_t)f0[3];
        p[4]=(bf16_t)f1[0]; p[5]=(bf16_t)f1[1]; p[6]=(bf16_t)f1[2]; p[7]=(bf16_t)f1[3];
        *(bf16x8*)(smem + row * 1536 + ((kq * 16) ^ ((row & 7) << 4))) = p;
    }
    __syncthreads();   // (2) embA visible

    // ---------------- stage 1: h = relu(emb @ w1 + b1)  [16x384] ----------
    f32x4 acc1[3];
#pragma unroll
    for (int j = 0; j < 3; ++j) acc1[j] = f32x4{0.f, 0.f, 0.f, 0.f};

#pragma unroll
    for (int kf = 0; kf < 24; ++kf) {
        int kb = (kf * 32 + l4 * 8) * 2;
        bf16x8 a0 = *(const bf16x8*)(smem + l15 * 1536 + (kb ^ ((l15 & 7) << 4)));
#pragma unroll
        for (int jn = 0; jn < 3; ++jn) {
            bf16x8 b = *(const bf16x8*)(w1e + ((size_t)(kf * 24 + wid * 3 + jn)) * 1024 + lane * 16);
            acc1[jn] = mfma16(a0, b, acc1[jn]);
        }
    }
    __syncthreads();   // (3) all embA reads done; region reusable for h

    // h = relu(acc1 + b1) -> bf16 swizzled LDS @ 0 (stride 768)
#pragma unroll
    for (int jn = 0; jn < 3; ++jn) {
        int col = wid * 48 + jn * 16 + l15;
        float bb = b1[e * H_DIM + col];
#pragma unroll
        for (int v = 0; v < 4; ++v) {
            int row = l4 * 4 + v;
            float hv = fmaxf(acc1[jn][v] + bb, 0.f);
            *(bf16_t*)(smem + row * 768 + ((col * 2) ^ ((row & 7) << 4))) = (bf16_t)hv;
        }
    }
    __syncthreads();   // (4) h visible

    // ---------------- stage 2: eo = h @ w4  [16x768] ----------------------
    f32x4 acc2[6];
#pragma unroll
    for (int j = 0; j < 6; ++j) acc2[j] = f32x4{0.f, 0.f, 0.f, 0.f};

#pragma unroll
    for (int kf = 0; kf < 12; ++kf) {
        int kb = (kf * 32 + l4 * 8) * 2;
        bf16x8 a0 = *(const bf16x8*)(smem + l15 * 768 + (kb ^ ((l15 & 7) << 4)));
#pragma unroll
        for (int jn = 0; jn < 6; ++jn) {
            bf16x8 b = *(const bf16x8*)(w4e + ((size_t)(kf * 48 + wid * 6 + jn)) * 1024 + lane * 16);
            acc2[jn] = mfma16(a0, b, acc2[jn]);
        }
    }

    // ---------------- epilogue: gate, l2norm, +emb, l2norm, scatter -------
    const int colb = wid * 96;
    float part[4];
#pragma unroll
    for (int v = 0; v < 4; ++v) part[v] = 0.f;

#pragma unroll
    for (int jn = 0; jn < 6; ++jn) {
        float bb = b4[e * D_DIM + colb + jn * 16 + l15];
#pragma unroll
        for (int v = 0; v < 4; ++v) {
            float cv = (acc2[jn][v] + bb) * gateL[l4 * 4 + v];
            acc2[jn][v] = cv;
            part[v] += cv * cv;
        }
    }
#pragma unroll
    for (int o = 1; o < 16; o <<= 1)
#pragma unroll
        for (int v = 0; v < 4; ++v) part[v] += __shfl_xor(part[v], o, 64);
    if (l15 == 0)
#pragma unroll
        for (int v = 0; v < 4; ++v) ssb1[(l4 * 4 + v) * 8 + wid] = part[v];
    __syncthreads();   // (5) ssb1 ready

    int   rofs[4];
    float inv1[4];
#pragma unroll
    for (int v = 0; v < 4; ++v) {
        int row = l4 * 4 + v;
        rofs[v] = ridxL[row] * D_DIM;
        float s = 0.f;
#pragma unroll
        for (int w = 0; w < 8; ++w) s += ssb1[row * 8 + w];
        inv1[v] = 1.0f / fmaxf(sqrtf(s), 1e-6f);
    }

    float part2[4];
#pragma unroll
    for (int v = 0; v < 4; ++v) part2[v] = 0.f;

#pragma unroll
    for (int jn = 0; jn < 6; ++jn) {
        int col = colb + jn * 16 + l15;
#pragma unroll
        for (int v = 0; v < 4; ++v) {
            float em = emb[rofs[v] + col];
            float o2 = acc2[jn][v] * inv1[v] + em;
            acc2[jn][v] = o2;
            part2[v] += o2 * o2;
        }
    }
#pragma unroll
    for (int o = 1; o < 16; o <<= 1)
#pragma unroll
        for (int v = 0; v < 4; ++v) part2[v] += __shfl_xor(part2[v], o, 64);
    if (l15 == 0)
#pragma unroll
        for (int v = 0; v < 4; ++v) ssb2[(l4 * 4 + v) * 8 + wid] = part2[v];
    __syncthreads();   // (6) ssb2 ready

#pragma unroll
    for (int v = 0; v < 4; ++v) {
        int row = l4 * 4 + v;
        float s = 0.f;
#pragma unroll
        for (int w = 0; w < 8; ++w) s += ssb2[row * 8 + w];
        float inv2 = 1.0f / fmaxf(sqrtf(s), 1e-12f);
        if (row < Meff) {
#pragma unroll
            for (int jn = 0; jn < 6; ++jn)
                out[rofs[v] + colb + jn * 16 + l15] = acc2[jn][v] * inv2;
        }
    }
}

// ---------------------------------------------------------------------------
extern "C" void kernel_launch(void* const* d_in, const int* in_sizes, int n_in,
                              void* d_out, int out_size, void* d_ws, size_t ws_size,
                              hipStream_t stream) {
    const float* emb    = (const float*)d_in[0];
    const float* logits = (const float*)d_in[1];
    const float* w1     = (const float*)d_in[2];
    const float* b1     = (const float*)d_in[3];
    const float* w4     = (const float*)d_in[4];
    const float* b4     = (const float*)d_in[5];
    float* out = (float*)d_out;
    char*  ws  = (char*)d_ws;
    if (ws_size < WS_END) return;  // workspace too small -> fail loudly

    int*   cnt     = (int*)(ws + WS_CNT);
    int*   cur     = (int*)(ws + WS_CUR);
    int*   offs    = (int*)(ws + WS_OFF);
    int*   toff    = (int*)(ws + WS_TOFF);
    int*   expert  = (int*)(ws + WS_EXP);
    float* gatev   = (float*)(ws + WS_GATE);
    int*   rowlist = (int*)(ws + WS_ROW);
    char*  w1s     = ws + WS_W1;
    char*  w4s     = ws + WS_W4;

    hipMemsetAsync(ws, 0, 512, stream);
    // weights convert (2304 blocks) + gate (32 blocks) in one dispatch
    prep<<<dim3(2336), dim3(512), 0, stream>>>(w1, w4, logits, w1s, w4s,
                                               expert, gatev, cnt);
    scank<<<dim3(1), dim3(64), 0, stream>>>(cnt, offs, toff);
    scatk<<<dim3(32), dim3(512), 0, stream>>>(expert, offs, cur, rowlist);

    (void)hipFuncSetAttribute((const void*)moe_main,
                              hipFuncAttributeMaxDynamicSharedMemorySize, SMEM_BYTES);
    // max tiles = sum_e ceil(cnt_e/16) <= 1040; grid 1040 = 8*130 (swizzle)
    moe_main<<<dim3(1040), dim3(512), SMEM_BYTES, stream>>>(
        emb, gatev, rowlist, cnt, offs, toff, w1s, w4s, b1, b4, out);
}